// Round 7
// baseline (455.145 us; speedup 1.0000x reference)
//
#include <hip/hip_runtime.h>
#include <hip/hip_bf16.h>

// Problem constants (fixed by the reference setup)
#define NN 50000
#define EE 800000
#define DIN 128
#define HH 128
#define DOUT 64
#define BN_EPS 1e-5f

typedef __attribute__((ext_vector_type(8))) short short8;   // 8 bf16 (4 VGPRs)
typedef __attribute__((ext_vector_type(4))) float floatx4;  // MFMA acc

static inline size_t align_up(size_t x, size_t a) { return (x + a - 1) & ~(a - 1); }

// bf16 <-> f32 helpers (RNE round)
__device__ __forceinline__ float bf2f(ushort u) {
    uint v = ((uint)u) << 16;
    return __builtin_bit_cast(float, v);
}
__device__ __forceinline__ float bf2f_lo(uint u) { return __builtin_bit_cast(float, u << 16); }
__device__ __forceinline__ float bf2f_hi(uint u) { return __builtin_bit_cast(float, u & 0xffff0000u); }
__device__ __forceinline__ ushort f2bf(float f) {
    uint u = __builtin_bit_cast(uint, f);
    u += 0x7fff + ((u >> 16) & 1);
    return (ushort)(u >> 16);
}
__device__ __forceinline__ uint pack_bf2(float lo, float hi) {
    return (uint)f2bf(lo) | ((uint)f2bf(hi) << 16);
}

// ---------------------------------------------------------------------------
// All 7 weights in one dispatch: W[k][f] f32 -> Wt[f][k] bf16 (k contiguous)
// ---------------------------------------------------------------------------
__global__ void tcast_all_kernel(const float* __restrict__ s0, const float* __restrict__ s1,
                                 const float* __restrict__ s2, const float* __restrict__ s3,
                                 const float* __restrict__ s4, const float* __restrict__ s5,
                                 const float* __restrict__ s6,
                                 ushort* __restrict__ d0, ushort* __restrict__ d1,
                                 ushort* __restrict__ d2, ushort* __restrict__ d3,
                                 ushort* __restrict__ d4, ushort* __restrict__ d5,
                                 ushort* __restrict__ d6) {
    const float* src; ushort* dst; int F = 128;
    switch (blockIdx.y) {
        case 0: src = s0; dst = d0; break;
        case 1: src = s1; dst = d1; break;
        case 2: src = s2; dst = d2; break;
        case 3: src = s3; dst = d3; break;
        case 4: src = s4; dst = d4; break;
        case 5: src = s5; dst = d5; break;
        default: src = s6; dst = d6; F = 64; break;
    }
    int t = blockIdx.x * 256 + threadIdx.x;
    if (t >= F * 128) return;
    int f = t >> 7, k = t & 127;
    dst[t] = f2bf(src[(size_t)k * F + f]);
}

// ---------------------------------------------------------------------------
// Graph preprocessing
// ---------------------------------------------------------------------------
__global__ void cnt_kernel(const int* __restrict__ ei, int* __restrict__ cnt, int E) {
    int e = (blockIdx.x * 256 + threadIdx.x) * 4;
    if (e + 3 < E) {
        int4 d = *(const int4*)(ei + E + e);
        atomicAdd(&cnt[d.x], 1);
        atomicAdd(&cnt[d.y], 1);
        atomicAdd(&cnt[d.z], 1);
        atomicAdd(&cnt[d.w], 1);
    } else {
        for (; e < E; ++e) atomicAdd(&cnt[ei[E + e]], 1);
    }
}

__device__ __forceinline__ void block_scan256(int v, int* lsum, int& excl, int& total) {
    int lane = threadIdx.x & 63, w = threadIdx.x >> 6;
    int inc = v;
    #pragma unroll
    for (int s = 1; s < 64; s <<= 1) {
        int t = __shfl_up(inc, s);
        if (lane >= s) inc += t;
    }
    if (lane == 63) lsum[w] = inc;
    __syncthreads();
    int pre = 0;
    #pragma unroll
    for (int k = 0; k < 4; ++k)
        if (k < w) pre += lsum[k];
    excl = pre + inc - v;
    total = lsum[0] + lsum[1] + lsum[2] + lsum[3];
    __syncthreads();
}

// partial exclusive scan into off; block sums; dinv fused in
__global__ void scan_part_kernel(const int* __restrict__ cnt, int* __restrict__ off,
                                 int* __restrict__ bsum, float* __restrict__ dinv, int n) {
    __shared__ int lsum[4];
    int i = blockIdx.x * 256 + threadIdx.x;
    int v = (i < n) ? cnt[i] : 0;
    int excl, total;
    block_scan256(v, lsum, excl, total);
    if (i < n) {
        off[i] = excl;
        dinv[i] = rsqrtf((float)(v + 1));
    }
    if (threadIdx.x == 0) bsum[blockIdx.x] = total;
}

__global__ void scan_bsum_kernel(int* __restrict__ bsum, int nb) {
    __shared__ int lsum[4];
    int t = threadIdx.x;
    int v = (t < nb) ? bsum[t] : 0;
    int excl, total;
    block_scan256(v, lsum, excl, total);
    if (t < nb) bsum[t] = excl;
}

// finalize off and initialize cursor = off (fill then needs no off read)
__global__ void scan_add_kernel(int* __restrict__ off, const int* __restrict__ bsum,
                                int* __restrict__ cursor, int n) {
    int i = blockIdx.x * 256 + threadIdx.x;
    if (i < n) {
        int v = off[i] + bsum[blockIdx.x];
        off[i] = v;
        cursor[i] = v;
    }
    if (i == 0) off[n] = EE;
}

// Scatter edges into CSR by destination; packed {src, w_bits} single 8B write.
// 4 edges per thread: 4 independent atomic+scatter chains (latency hiding).
__global__ void fill_kernel(const int* __restrict__ ei, int* __restrict__ cursor,
                            int2* __restrict__ csr, const float* __restrict__ dinv, int E) {
    int e = (blockIdx.x * 256 + threadIdx.x) * 4;
    if (e + 3 < E) {
        int4 s4 = *(const int4*)(ei + e);
        int4 d4 = *(const int4*)(ei + E + e);
        float wa = dinv[s4.x] * dinv[d4.x];
        float wb = dinv[s4.y] * dinv[d4.y];
        float wc = dinv[s4.z] * dinv[d4.z];
        float wd = dinv[s4.w] * dinv[d4.w];
        int pa = atomicAdd(&cursor[d4.x], 1);
        int pb = atomicAdd(&cursor[d4.y], 1);
        int pc = atomicAdd(&cursor[d4.z], 1);
        int pd = atomicAdd(&cursor[d4.w], 1);
        csr[pa] = make_int2(s4.x, __builtin_bit_cast(int, wa));
        csr[pb] = make_int2(s4.y, __builtin_bit_cast(int, wb));
        csr[pc] = make_int2(s4.z, __builtin_bit_cast(int, wc));
        csr[pd] = make_int2(s4.w, __builtin_bit_cast(int, wd));
    } else {
        for (; e < E; ++e) {
            int s = ei[e];
            int d = ei[E + e];
            float w = dinv[s] * dinv[d];
            int pos = atomicAdd(&cursor[d], 1);
            csr[pos] = make_int2(s, __builtin_bit_cast(int, w));
        }
    }
}

// ---------------------------------------------------------------------------
// Shared MFMA building blocks. LDS layout: [row/f][16 uint4-chunks] with
// chunk index XOR-swizzled by (row&15) -> ds_read_b128 is 2-way (free).
// ---------------------------------------------------------------------------
template <int NCG>
__device__ __forceinline__ void zero_acc(floatx4 (&acc)[2][NCG]) {
    #pragma unroll
    for (int rg = 0; rg < 2; ++rg)
        #pragma unroll
        for (int cg = 0; cg < NCG; ++cg)
            acc[rg][cg] = (floatx4){0.f, 0.f, 0.f, 0.f};
}

template <int FO>
__device__ __forceinline__ void stage_w(const ushort* __restrict__ Wt, uint4* Wl, int tid) {
    #pragma unroll
    for (int c = tid; c < FO * 16; c += 256) {
        int f = c >> 4, kb = c & 15;
        Wl[f * 16 + (kb ^ (f & 15))] = ((const uint4*)Wt)[c];
    }
}

template <int NCG>
__device__ __forceinline__ void gemm_step(const uint4* Xl, const uint4* Wl,
                                          floatx4 (&acc)[2][NCG], int wv, int lr, int lk) {
    #pragma unroll
    for (int ks = 0; ks < 4; ++ks) {
        int kb = ks * 4 + lk;
        int swz = kb ^ lr;
        short8 a0 = *(const short8*)&Xl[(wv * 32 + lr) * 16 + swz];
        short8 a1 = *(const short8*)&Xl[(wv * 32 + 16 + lr) * 16 + swz];
        #pragma unroll
        for (int cg = 0; cg < NCG; ++cg) {
            short8 b = *(const short8*)&Wl[(cg * 16 + lr) * 16 + swz];
            acc[0][cg] = __builtin_amdgcn_mfma_f32_16x16x32_bf16(a0, b, acc[0][cg], 0, 0, 0);
            acc[1][cg] = __builtin_amdgcn_mfma_f32_16x16x32_bf16(a1, b, acc[1][cg], 0, 0, 0);
        }
    }
}

// write H = relu(acc + bias) back into the X LDS buffer (bf16, same swizzle)
template <int NCG>
__device__ __forceinline__ void write_h(floatx4 (&acc)[2][NCG], uint4* Xl,
                                        const float* __restrict__ bias,
                                        int wv, int lr, int lk) {
    ushort* Xs = (ushort*)Xl;
    #pragma unroll
    for (int rg = 0; rg < 2; ++rg)
        #pragma unroll
        for (int cg = 0; cg < NCG; ++cg) {
            int col = cg * 16 + lr;
            float bv = bias[col];
            #pragma unroll
            for (int j = 0; j < 4; ++j) {
                int row = wv * 32 + rg * 16 + lk * 4 + j;
                float o = fmaxf(acc[rg][cg][j] + bv, 0.f);
                Xs[(row * 16 + ((col >> 3) ^ (row & 15))) * 8 + (col & 7)] = f2bf(o);
            }
        }
}

template <int FOUT, bool RELU, bool BIAS, bool OUTF32>
__device__ __forceinline__ void epilogue(floatx4 (&acc)[2][FOUT / 16],
                                         const float* __restrict__ bias, void* Yout,
                                         int row0, int n, int wv, int lr, int lk) {
    #pragma unroll
    for (int rg = 0; rg < 2; ++rg) {
        int rbase = row0 + wv * 32 + rg * 16 + lk * 4;
        #pragma unroll
        for (int cg = 0; cg < FOUT / 16; ++cg) {
            int col = cg * 16 + lr;
            float bv = BIAS ? bias[col] : 0.f;
            #pragma unroll
            for (int j = 0; j < 4; ++j) {
                int r = rbase + j;
                if (r < n) {
                    float o = acc[rg][cg][j] + bv;
                    if (RELU) o = fmaxf(o, 0.f);
                    if (OUTF32)
                        ((float*)Yout)[(size_t)r * FOUT + col] = o;
                    else
                        ((ushort*)Yout)[(size_t)r * FOUT + col] = f2bf(o);
                }
            }
        }
    }
}

// ---------------------------------------------------------------------------
// Fused pre-MLP + conv0 GEMM: P = relu(relu(X@W1+b1)@W2+b2)@W0c
// ---------------------------------------------------------------------------
__global__ __launch_bounds__(256, 2) void fused_pre_kernel(
    const float* __restrict__ Xg, const ushort* __restrict__ W1t, const float* __restrict__ b1,
    const ushort* __restrict__ W2t, const float* __restrict__ b2,
    const ushort* __restrict__ W3t, ushort* __restrict__ Yout, int n) {
    __shared__ uint4 lds4[4096];
    uint4* Xl = lds4;
    uint4* Wl = lds4 + 2048;
    const int tid = threadIdx.x;
    const int row0 = blockIdx.x * 128;

    // stage X with f32->bf16 cast
    for (int c = tid; c < 2048; c += 256) {
        int r = c >> 4, kb = c & 15;
        int row = row0 + r;
        uint4 v = make_uint4(0, 0, 0, 0);
        if (row < n) {
            const float4* p = (const float4*)(Xg + (size_t)row * 128 + kb * 8);
            float4 x0 = p[0], x1 = p[1];
            v.x = pack_bf2(x0.x, x0.y);
            v.y = pack_bf2(x0.z, x0.w);
            v.z = pack_bf2(x1.x, x1.y);
            v.w = pack_bf2(x1.z, x1.w);
        }
        Xl[r * 16 + (kb ^ (r & 15))] = v;
    }
    stage_w<128>(W1t, Wl, tid);
    __syncthreads();

    const int wv = tid >> 6, lane = tid & 63;
    const int lr = lane & 15, lk = lane >> 4;

    floatx4 acc[2][8];
    zero_acc<8>(acc);
    gemm_step<8>(Xl, Wl, acc, wv, lr, lk);
    __syncthreads();
    write_h<8>(acc, Xl, b1, wv, lr, lk);
    stage_w<128>(W2t, Wl, tid);
    __syncthreads();

    zero_acc<8>(acc);
    gemm_step<8>(Xl, Wl, acc, wv, lr, lk);
    __syncthreads();
    write_h<8>(acc, Xl, b2, wv, lr, lk);
    stage_w<128>(W3t, Wl, tid);
    __syncthreads();

    zero_acc<8>(acc);
    gemm_step<8>(Xl, Wl, acc, wv, lr, lk);
    epilogue<128, false, false, false>(acc, nullptr, Yout, row0, n, wv, lr, lk);
}

// ---------------------------------------------------------------------------
// Fused post-MLP: out = relu(X@W1+b1)@W2 + b2   (f32 output, DOUT=64)
// ---------------------------------------------------------------------------
__global__ __launch_bounds__(256, 2) void fused_post_kernel(
    const ushort* __restrict__ Xg, const ushort* __restrict__ W1t, const float* __restrict__ b1,
    const ushort* __restrict__ W2t, const float* __restrict__ b2,
    float* __restrict__ Yout, int n) {
    __shared__ uint4 lds4[4096];
    uint4* Xl = lds4;
    uint4* Wl = lds4 + 2048;
    const int tid = threadIdx.x;
    const int row0 = blockIdx.x * 128;

    for (int c = tid; c < 2048; c += 256) {
        int r = c >> 4, kb = c & 15;
        int row = row0 + r;
        uint4 v = make_uint4(0, 0, 0, 0);
        if (row < n) v = ((const uint4*)(Xg + (size_t)row * 128))[kb];
        Xl[r * 16 + (kb ^ (r & 15))] = v;
    }
    stage_w<128>(W1t, Wl, tid);
    __syncthreads();

    const int wv = tid >> 6, lane = tid & 63;
    const int lr = lane & 15, lk = lane >> 4;

    floatx4 acc[2][8];
    zero_acc<8>(acc);
    gemm_step<8>(Xl, Wl, acc, wv, lr, lk);
    __syncthreads();
    write_h<8>(acc, Xl, b1, wv, lr, lk);
    stage_w<64>(W2t, Wl, tid);
    __syncthreads();

    floatx4 acc2[2][4];
    zero_acc<4>(acc2);
    gemm_step<4>(Xl, Wl, acc2, wv, lr, lk);
    epilogue<64, false, true, true>(acc2, b2, Yout, row0, n, wv, lr, lk);
}

// ---------------------------------------------------------------------------
// Single GEMM with BatchNorm+ReLU folded into X staging; coefs computed
// in-kernel from raw sums/sumsq.
// ---------------------------------------------------------------------------
__global__ __launch_bounds__(256, 2) void gemm_bnf_kernel(
    const ushort* __restrict__ Xg, const ushort* __restrict__ Wt,
    const float* __restrict__ sums, const float* __restrict__ sumsq,
    const float* __restrict__ g, const float* __restrict__ bb,
    ushort* __restrict__ Yout, int n) {
    __shared__ uint4 lds4[4096];
    __shared__ float scf[128], shf[128];
    uint4* Xl = lds4;
    uint4* Wl = lds4 + 2048;
    const int tid = threadIdx.x;
    const int row0 = blockIdx.x * 128;

    if (tid < 128) {
        const float inv_n = 1.0f / (float)NN;
        float m = sums[tid] * inv_n;
        float var = sumsq[tid] * inv_n - m * m;
        float sc = g[tid] * rsqrtf(var + BN_EPS);
        scf[tid] = sc;
        shf[tid] = bb[tid] - m * sc;
    }
    stage_w<128>(Wt, Wl, tid);
    __syncthreads();

    for (int c = tid; c < 2048; c += 256) {
        int r = c >> 4, kb = c & 15;
        int row = row0 + r;
        uint4 v = make_uint4(0, 0, 0, 0);
        if (row < n) v = ((const uint4*)(Xg + (size_t)row * 128))[kb];
        uint a[4] = {v.x, v.y, v.z, v.w};
        #pragma unroll
        for (int p = 0; p < 4; ++p) {
            int f0 = kb * 8 + p * 2;
            float lo = fmaxf(fmaf(bf2f_lo(a[p]), scf[f0], shf[f0]), 0.f);
            float hi = fmaxf(fmaf(bf2f_hi(a[p]), scf[f0 + 1], shf[f0 + 1]), 0.f);
            a[p] = pack_bf2(lo, hi);
        }
        Xl[r * 16 + (kb ^ (r & 15))] = make_uint4(a[0], a[1], a[2], a[3]);
    }
    __syncthreads();

    const int wv = tid >> 6, lane = tid & 63;
    const int lr = lane & 15, lk = lane >> 4;

    floatx4 acc[2][8];
    zero_acc<8>(acc);
    gemm_step<8>(Xl, Wl, acc, wv, lr, lk);
    epilogue<128, false, false, false>(acc, nullptr, Yout, row0, n, wv, lr, lk);
}

// ---------------------------------------------------------------------------
// Quarter-split aggregation with packed edges: out[i,f] = sum_e h[src,f]*w_e
//   + h[i,f]*dinv[i]^2 + bias[f], f in quarter q.
// Block = 16 nodes x 32 features. Wave = 4 nodes x 16 lanes. Quarter-major
// grid keeps a 3.2 MB quarter of h L2-resident. Edge record int2{src,w}
// broadcast-loads per 16-lane group; h gather is the only random access.
// ---------------------------------------------------------------------------
#define AGG_CPQ (NN / 16)   // 3125 blocks per quarter
__global__ __launch_bounds__(256) void aggq_kernel(const ushort* __restrict__ h,
                                                   const float* __restrict__ dinv,
                                                   const int* __restrict__ off,
                                                   const int2* __restrict__ csr,
                                                   const float* __restrict__ bias,
                                                   ushort* __restrict__ out) {
    const int q = blockIdx.x / AGG_CPQ;
    const int c = blockIdx.x % AGG_CPQ;
    const int tid = threadIdx.x;
    const int wv = tid >> 6, l = tid & 63;
    const int g = l >> 4, l16 = l & 15;
    const int node = c * 16 + wv * 4 + g;
    const int base = q * 16 + l16;            // uint index within row (64 uints)

    const uint* __restrict__ hq = (const uint*)h;
    float di = dinv[node];
    uint u = hq[(size_t)node * 64 + base];
    float sw = di * di;
    float a0 = bf2f_lo(u) * sw, a1 = bf2f_hi(u) * sw;

    const int s0 = off[node], s1 = off[node + 1];
    int j = s0;
    for (; j + 4 <= s1; j += 4) {
        int2 ea = csr[j + 0], eb = csr[j + 1];
        int2 ec = csr[j + 2], ed = csr[j + 3];
        float wa = __builtin_bit_cast(float, ea.y), wb = __builtin_bit_cast(float, eb.y);
        float wc = __builtin_bit_cast(float, ec.y), wd = __builtin_bit_cast(float, ed.y);
        uint ua = hq[(size_t)ea.x * 64 + base];
        uint ub = hq[(size_t)eb.x * 64 + base];
        uint uc = hq[(size_t)ec.x * 64 + base];
        uint ud = hq[(size_t)ed.x * 64 + base];
        a0 += bf2f_lo(ua) * wa + bf2f_lo(ub) * wb + bf2f_lo(uc) * wc + bf2f_lo(ud) * wd;
        a1 += bf2f_hi(ua) * wa + bf2f_hi(ub) * wb + bf2f_hi(uc) * wc + bf2f_hi(ud) * wd;
    }
    for (; j < s1; ++j) {
        int2 e = csr[j];
        float w = __builtin_bit_cast(float, e.y);
        uint uv = hq[(size_t)e.x * 64 + base];
        a0 += bf2f_lo(uv) * w;
        a1 += bf2f_hi(uv) * w;
    }

    float2 b2 = ((const float2*)bias)[base];
    a0 += b2.x; a1 += b2.y;
    ((uint*)out)[(size_t)node * 64 + base] = pack_bf2(a0, a1);
}

// ---------------------------------------------------------------------------
// BatchNorm statistics: vectorized uint4 (8 bf16) loads, LDS reduce, atomics.
// ---------------------------------------------------------------------------
__global__ __launch_bounds__(256) void bn_stats16_kernel(const ushort* __restrict__ x,
                                                         float* __restrict__ sums,
                                                         float* __restrict__ sumsq, int n) {
    __shared__ float ls[128], lq[128];
    int tid = threadIdx.x;
    if (tid < 128) { ls[tid] = 0.f; lq[tid] = 0.f; }
    __syncthreads();
    int fg = tid & 15, rg = tid >> 4;
    float s[8] = {}, q[8] = {};
    for (int r = blockIdx.x * 16 + rg; r < n; r += gridDim.x * 16) {
        uint4 v = ((const uint4*)(x + (size_t)r * 128))[fg];
        uint a[4] = {v.x, v.y, v.z, v.w};
        #pragma unroll
        for (int p = 0; p < 4; ++p) {
            float lo = bf2f_lo(a[p]), hi = bf2f_hi(a[p]);
            s[2 * p] += lo;     q[2 * p] += lo * lo;
            s[2 * p + 1] += hi; q[2 * p + 1] += hi * hi;
        }
    }
    #pragma unroll
    for (int k = 0; k < 8; ++k) {
        atomicAdd(&ls[fg * 8 + k], s[k]);
        atomicAdd(&lq[fg * 8 + k], q[k]);
    }
    __syncthreads();
    if (tid < 128) {
        atomicAdd(&sums[tid], ls[tid]);
        atomicAdd(&sumsq[tid], lq[tid]);
    }
}

// ---------------------------------------------------------------------------
extern "C" void kernel_launch(void* const* d_in, const int* in_sizes, int n_in,
                              void* d_out, int out_size, void* d_ws, size_t ws_size,
                              hipStream_t stream) {
    const float* x        = (const float*)d_in[0];
    const int*   ei       = (const int*)d_in[1];
    const float* pre_w1   = (const float*)d_in[2];
    const float* pre_b1   = (const float*)d_in[3];
    const float* pre_w2   = (const float*)d_in[4];
    const float* pre_b2   = (const float*)d_in[5];
    const float* conv_w0  = (const float*)d_in[6];
    const float* conv_b0  = (const float*)d_in[7];
    const float* conv_w1  = (const float*)d_in[8];
    const float* conv_b1  = (const float*)d_in[9];
    const float* conv_w2  = (const float*)d_in[10];
    const float* conv_b2  = (const float*)d_in[11];
    const float* bn_g0    = (const float*)d_in[12];
    const float* bn_b0    = (const float*)d_in[13];
    const float* bn_g1    = (const float*)d_in[14];
    const float* bn_b1    = (const float*)d_in[15];
    const float* post_w1  = (const float*)d_in[16];
    const float* post_b1  = (const float*)d_in[17];
    const float* post_w2  = (const float*)d_in[18];
    const float* post_b2  = (const float*)d_in[19];
    float* out = (float*)d_out;

    const int n = NN, E = EE;
    const int NB = (n + 255) / 256;

    // Workspace layout (cnt followed by BN sums region -> single memset)
    char* w = (char*)d_ws;
    int* cnt    = (int*)w;   w += (size_t)n * 4;          // 16B-aligned
    float* bns0 = (float*)w; // sums0, sumsq0, sums1, sumsq1 (512 floats)
    float* bnq0 = bns0 + 128;
    float* bns1 = bns0 + 256;
    float* bnq1 = bns0 + 384;
    w += align_up(512 * 4, 512);
    int* cursor = (int*)w;   w += align_up((size_t)n * 4, 512);
    int* bsum   = (int*)w;   w += align_up(256 * 4, 512);
    int* off    = (int*)w;   w += align_up((size_t)(n + 1) * 4, 512);
    float* dinv = (float*)w; w += align_up((size_t)n * 4, 512);
    int2* csr   = (int2*)w;  w += align_up((size_t)E * 8, 512);
    ushort* wt_pre1  = (ushort*)w; w += align_up(128 * 128 * 2, 512);
    ushort* wt_pre2  = (ushort*)w; w += align_up(128 * 128 * 2, 512);
    ushort* wt_c0    = (ushort*)w; w += align_up(128 * 128 * 2, 512);
    ushort* wt_c1    = (ushort*)w; w += align_up(128 * 128 * 2, 512);
    ushort* wt_c2    = (ushort*)w; w += align_up(128 * 128 * 2, 512);
    ushort* wt_post1 = (ushort*)w; w += align_up(128 * 128 * 2, 512);
    ushort* wt_post2 = (ushort*)w; w += align_up(64 * 128 * 2, 512);
    ushort* P = (ushort*)w; w += align_up((size_t)n * 128 * 2, 512);
    ushort* Q = (ushort*)w; w += align_up((size_t)n * 128 * 2, 512);
    ushort* R = (ushort*)w; w += align_up((size_t)n * 128 * 2, 512);

    hipMemsetAsync(cnt, 0, (size_t)n * 4 + 512 * 4, stream);

    // Weight transposes/casts (one dispatch)
    tcast_all_kernel<<<dim3(64, 7), 256, 0, stream>>>(
        pre_w1, pre_w2, conv_w0, conv_w1, conv_w2, post_w1, post_w2,
        wt_pre1, wt_pre2, wt_c0, wt_c1, wt_c2, wt_post1, wt_post2);

    // Graph preprocessing
    cnt_kernel<<<(E / 4 + 255) / 256, 256, 0, stream>>>(ei, cnt, E);
    scan_part_kernel<<<NB, 256, 0, stream>>>(cnt, off, bsum, dinv, n);
    scan_bsum_kernel<<<1, 256, 0, stream>>>(bsum, NB);
    scan_add_kernel<<<NB, 256, 0, stream>>>(off, bsum, cursor, n);
    fill_kernel<<<(E / 4 + 255) / 256, 256, 0, stream>>>(ei, cursor, csr, dinv, E);

    const int gb = (n + 127) / 128;
    const int agg_blocks = 4 * AGG_CPQ;   // 4 quarters x 3125

    // pre-MLP + conv0 (fused)
    fused_pre_kernel<<<gb, 256, 0, stream>>>(x, wt_pre1, pre_b1, wt_pre2, pre_b2, wt_c0, P, n);
    aggq_kernel<<<agg_blocks, 256, 0, stream>>>(P, dinv, off, csr, conv_b0, Q);
    bn_stats16_kernel<<<256, 256, 0, stream>>>(Q, bns0, bnq0, n);

    // conv1 (BN0 fold, coef in-kernel)
    gemm_bnf_kernel<<<gb, 256, 0, stream>>>(Q, wt_c1, bns0, bnq0, bn_g0, bn_b0, P, n);
    aggq_kernel<<<agg_blocks, 256, 0, stream>>>(P, dinv, off, csr, conv_b1, R);
    bn_stats16_kernel<<<256, 256, 0, stream>>>(R, bns1, bnq1, n);

    // conv2 (BN1 fold)
    gemm_bnf_kernel<<<gb, 256, 0, stream>>>(R, wt_c2, bns1, bnq1, bn_g1, bn_b1, P, n);
    aggq_kernel<<<agg_blocks, 256, 0, stream>>>(P, dinv, off, csr, conv_b2, Q);

    // post-MLP (fused)
    fused_post_kernel<<<gb, 256, 0, stream>>>(Q, wt_post1, post_b1, wt_post2, post_b2, out, n);
}

// Round 8
// 406.963 us; speedup vs baseline: 1.1184x; 1.1184x over previous
//
#include <hip/hip_runtime.h>
#include <hip/hip_bf16.h>

// Problem constants (fixed by the reference setup)
#define NN 50000
#define EE 800000
#define DIN 128
#define HH 128
#define DOUT 64
#define BN_EPS 1e-5f

typedef __attribute__((ext_vector_type(8))) short short8;   // 8 bf16 (4 VGPRs)
typedef __attribute__((ext_vector_type(4))) float floatx4;  // MFMA acc

static inline size_t align_up(size_t x, size_t a) { return (x + a - 1) & ~(a - 1); }

// bf16 <-> f32 helpers (RNE round)
__device__ __forceinline__ float bf2f(ushort u) {
    uint v = ((uint)u) << 16;
    return __builtin_bit_cast(float, v);
}
__device__ __forceinline__ float bf2f_lo(uint u) { return __builtin_bit_cast(float, u << 16); }
__device__ __forceinline__ float bf2f_hi(uint u) { return __builtin_bit_cast(float, u & 0xffff0000u); }
__device__ __forceinline__ ushort f2bf(float f) {
    uint u = __builtin_bit_cast(uint, f);
    u += 0x7fff + ((u >> 16) & 1);
    return (ushort)(u >> 16);
}
__device__ __forceinline__ uint pack_bf2(float lo, float hi) {
    return (uint)f2bf(lo) | ((uint)f2bf(hi) << 16);
}

// ---------------------------------------------------------------------------
// All 7 weights in one dispatch: W[k][f] f32 -> Wt[f][k] bf16 (k contiguous)
// ---------------------------------------------------------------------------
__global__ void tcast_all_kernel(const float* __restrict__ s0, const float* __restrict__ s1,
                                 const float* __restrict__ s2, const float* __restrict__ s3,
                                 const float* __restrict__ s4, const float* __restrict__ s5,
                                 const float* __restrict__ s6,
                                 ushort* __restrict__ d0, ushort* __restrict__ d1,
                                 ushort* __restrict__ d2, ushort* __restrict__ d3,
                                 ushort* __restrict__ d4, ushort* __restrict__ d5,
                                 ushort* __restrict__ d6) {
    const float* src; ushort* dst; int F = 128;
    switch (blockIdx.y) {
        case 0: src = s0; dst = d0; break;
        case 1: src = s1; dst = d1; break;
        case 2: src = s2; dst = d2; break;
        case 3: src = s3; dst = d3; break;
        case 4: src = s4; dst = d4; break;
        case 5: src = s5; dst = d5; break;
        default: src = s6; dst = d6; F = 64; break;
    }
    int t = blockIdx.x * 256 + threadIdx.x;
    if (t >= F * 128) return;
    int f = t >> 7, k = t & 127;
    dst[t] = f2bf(src[(size_t)k * F + f]);
}

// ---------------------------------------------------------------------------
// Graph preprocessing
// ---------------------------------------------------------------------------
__global__ void cnt_kernel(const int* __restrict__ ei, int* __restrict__ cnt, int E) {
    int e = (blockIdx.x * 256 + threadIdx.x) * 4;
    if (e + 3 < E) {
        int4 d = *(const int4*)(ei + E + e);
        atomicAdd(&cnt[d.x], 1);
        atomicAdd(&cnt[d.y], 1);
        atomicAdd(&cnt[d.z], 1);
        atomicAdd(&cnt[d.w], 1);
    } else {
        for (; e < E; ++e) atomicAdd(&cnt[ei[E + e]], 1);
    }
}

__device__ __forceinline__ void block_scan256(int v, int* lsum, int& excl, int& total) {
    int lane = threadIdx.x & 63, w = threadIdx.x >> 6;
    int inc = v;
    #pragma unroll
    for (int s = 1; s < 64; s <<= 1) {
        int t = __shfl_up(inc, s);
        if (lane >= s) inc += t;
    }
    if (lane == 63) lsum[w] = inc;
    __syncthreads();
    int pre = 0;
    #pragma unroll
    for (int k = 0; k < 4; ++k)
        if (k < w) pre += lsum[k];
    excl = pre + inc - v;
    total = lsum[0] + lsum[1] + lsum[2] + lsum[3];
    __syncthreads();
}

// partial exclusive scan into off; block sums; dinv fused in
__global__ void scan_part_kernel(const int* __restrict__ cnt, int* __restrict__ off,
                                 int* __restrict__ bsum, float* __restrict__ dinv, int n) {
    __shared__ int lsum[4];
    int i = blockIdx.x * 256 + threadIdx.x;
    int v = (i < n) ? cnt[i] : 0;
    int excl, total;
    block_scan256(v, lsum, excl, total);
    if (i < n) {
        off[i] = excl;
        dinv[i] = rsqrtf((float)(v + 1));
    }
    if (threadIdx.x == 0) bsum[blockIdx.x] = total;
}

__global__ void scan_bsum_kernel(int* __restrict__ bsum, int nb) {
    __shared__ int lsum[4];
    int t = threadIdx.x;
    int v = (t < nb) ? bsum[t] : 0;
    int excl, total;
    block_scan256(v, lsum, excl, total);
    if (t < nb) bsum[t] = excl;
}

// finalize off and initialize cursor = off (fill then needs no off read)
__global__ void scan_add_kernel(int* __restrict__ off, const int* __restrict__ bsum,
                                int* __restrict__ cursor, int n) {
    int i = blockIdx.x * 256 + threadIdx.x;
    if (i < n) {
        int v = off[i] + bsum[blockIdx.x];
        off[i] = v;
        cursor[i] = v;
    }
    if (i == 0) off[n] = EE;
}

// Scatter edges into CSR by destination; packed {src, w_bits} single 8B write.
// 1 edge/thread, 3125 blocks (measured-best configuration, R5: 43.6 us).
__global__ void fill_kernel(const int* __restrict__ ei, int* __restrict__ cursor,
                            int2* __restrict__ csr, const float* __restrict__ dinv, int E) {
    int e = blockIdx.x * 256 + threadIdx.x;
    if (e < E) {
        int s = ei[e];
        int d = ei[E + e];
        float w = dinv[s] * dinv[d];
        int pos = atomicAdd(&cursor[d], 1);
        csr[pos] = make_int2(s, __builtin_bit_cast(int, w));
    }
}

// ---------------------------------------------------------------------------
// Shared MFMA building blocks. LDS layout: [row/f][16 uint4-chunks] with
// chunk index XOR-swizzled by (row&15) -> ds_read_b128 is 2-way (free).
// ---------------------------------------------------------------------------
template <int NCG>
__device__ __forceinline__ void zero_acc(floatx4 (&acc)[2][NCG]) {
    #pragma unroll
    for (int rg = 0; rg < 2; ++rg)
        #pragma unroll
        for (int cg = 0; cg < NCG; ++cg)
            acc[rg][cg] = (floatx4){0.f, 0.f, 0.f, 0.f};
}

template <int FO>
__device__ __forceinline__ void stage_w(const ushort* __restrict__ Wt, uint4* Wl, int tid) {
    #pragma unroll
    for (int c = tid; c < FO * 16; c += 256) {
        int f = c >> 4, kb = c & 15;
        Wl[f * 16 + (kb ^ (f & 15))] = ((const uint4*)Wt)[c];
    }
}

template <int NCG>
__device__ __forceinline__ void gemm_step(const uint4* Xl, const uint4* Wl,
                                          floatx4 (&acc)[2][NCG], int wv, int lr, int lk) {
    #pragma unroll
    for (int ks = 0; ks < 4; ++ks) {
        int kb = ks * 4 + lk;
        int swz = kb ^ lr;
        short8 a0 = *(const short8*)&Xl[(wv * 32 + lr) * 16 + swz];
        short8 a1 = *(const short8*)&Xl[(wv * 32 + 16 + lr) * 16 + swz];
        #pragma unroll
        for (int cg = 0; cg < NCG; ++cg) {
            short8 b = *(const short8*)&Wl[(cg * 16 + lr) * 16 + swz];
            acc[0][cg] = __builtin_amdgcn_mfma_f32_16x16x32_bf16(a0, b, acc[0][cg], 0, 0, 0);
            acc[1][cg] = __builtin_amdgcn_mfma_f32_16x16x32_bf16(a1, b, acc[1][cg], 0, 0, 0);
        }
    }
}

// write H = relu(acc + bias) back into the X LDS buffer (bf16, same swizzle)
template <int NCG>
__device__ __forceinline__ void write_h(floatx4 (&acc)[2][NCG], uint4* Xl,
                                        const float* __restrict__ bias,
                                        int wv, int lr, int lk) {
    ushort* Xs = (ushort*)Xl;
    #pragma unroll
    for (int rg = 0; rg < 2; ++rg)
        #pragma unroll
        for (int cg = 0; cg < NCG; ++cg) {
            int col = cg * 16 + lr;
            float bv = bias[col];
            #pragma unroll
            for (int j = 0; j < 4; ++j) {
                int row = wv * 32 + rg * 16 + lk * 4 + j;
                float o = fmaxf(acc[rg][cg][j] + bv, 0.f);
                Xs[(row * 16 + ((col >> 3) ^ (row & 15))) * 8 + (col & 7)] = f2bf(o);
            }
        }
}

template <int FOUT, bool RELU, bool BIAS, bool OUTF32>
__device__ __forceinline__ void epilogue(floatx4 (&acc)[2][FOUT / 16],
                                         const float* __restrict__ bias, void* Yout,
                                         int row0, int n, int wv, int lr, int lk) {
    #pragma unroll
    for (int rg = 0; rg < 2; ++rg) {
        int rbase = row0 + wv * 32 + rg * 16 + lk * 4;
        #pragma unroll
        for (int cg = 0; cg < FOUT / 16; ++cg) {
            int col = cg * 16 + lr;
            float bv = BIAS ? bias[col] : 0.f;
            #pragma unroll
            for (int j = 0; j < 4; ++j) {
                int r = rbase + j;
                if (r < n) {
                    float o = acc[rg][cg][j] + bv;
                    if (RELU) o = fmaxf(o, 0.f);
                    if (OUTF32)
                        ((float*)Yout)[(size_t)r * FOUT + col] = o;
                    else
                        ((ushort*)Yout)[(size_t)r * FOUT + col] = f2bf(o);
                }
            }
        }
    }
}

// ---------------------------------------------------------------------------
// Fused pre-MLP + conv0 GEMM: P = relu(relu(X@W1+b1)@W2+b2)@W0c
// ---------------------------------------------------------------------------
__global__ __launch_bounds__(256, 2) void fused_pre_kernel(
    const float* __restrict__ Xg, const ushort* __restrict__ W1t, const float* __restrict__ b1,
    const ushort* __restrict__ W2t, const float* __restrict__ b2,
    const ushort* __restrict__ W3t, ushort* __restrict__ Yout, int n) {
    __shared__ uint4 lds4[4096];
    uint4* Xl = lds4;
    uint4* Wl = lds4 + 2048;
    const int tid = threadIdx.x;
    const int row0 = blockIdx.x * 128;

    // stage X with f32->bf16 cast
    for (int c = tid; c < 2048; c += 256) {
        int r = c >> 4, kb = c & 15;
        int row = row0 + r;
        uint4 v = make_uint4(0, 0, 0, 0);
        if (row < n) {
            const float4* p = (const float4*)(Xg + (size_t)row * 128 + kb * 8);
            float4 x0 = p[0], x1 = p[1];
            v.x = pack_bf2(x0.x, x0.y);
            v.y = pack_bf2(x0.z, x0.w);
            v.z = pack_bf2(x1.x, x1.y);
            v.w = pack_bf2(x1.z, x1.w);
        }
        Xl[r * 16 + (kb ^ (r & 15))] = v;
    }
    stage_w<128>(W1t, Wl, tid);
    __syncthreads();

    const int wv = tid >> 6, lane = tid & 63;
    const int lr = lane & 15, lk = lane >> 4;

    floatx4 acc[2][8];
    zero_acc<8>(acc);
    gemm_step<8>(Xl, Wl, acc, wv, lr, lk);
    __syncthreads();
    write_h<8>(acc, Xl, b1, wv, lr, lk);
    stage_w<128>(W2t, Wl, tid);
    __syncthreads();

    zero_acc<8>(acc);
    gemm_step<8>(Xl, Wl, acc, wv, lr, lk);
    __syncthreads();
    write_h<8>(acc, Xl, b2, wv, lr, lk);
    stage_w<128>(W3t, Wl, tid);
    __syncthreads();

    zero_acc<8>(acc);
    gemm_step<8>(Xl, Wl, acc, wv, lr, lk);
    epilogue<128, false, false, false>(acc, nullptr, Yout, row0, n, wv, lr, lk);
}

// ---------------------------------------------------------------------------
// Fused post-MLP: out = relu(X@W1+b1)@W2 + b2   (f32 output, DOUT=64)
// ---------------------------------------------------------------------------
__global__ __launch_bounds__(256, 2) void fused_post_kernel(
    const ushort* __restrict__ Xg, const ushort* __restrict__ W1t, const float* __restrict__ b1,
    const ushort* __restrict__ W2t, const float* __restrict__ b2,
    float* __restrict__ Yout, int n) {
    __shared__ uint4 lds4[4096];
    uint4* Xl = lds4;
    uint4* Wl = lds4 + 2048;
    const int tid = threadIdx.x;
    const int row0 = blockIdx.x * 128;

    for (int c = tid; c < 2048; c += 256) {
        int r = c >> 4, kb = c & 15;
        int row = row0 + r;
        uint4 v = make_uint4(0, 0, 0, 0);
        if (row < n) v = ((const uint4*)(Xg + (size_t)row * 128))[kb];
        Xl[r * 16 + (kb ^ (r & 15))] = v;
    }
    stage_w<128>(W1t, Wl, tid);
    __syncthreads();

    const int wv = tid >> 6, lane = tid & 63;
    const int lr = lane & 15, lk = lane >> 4;

    floatx4 acc[2][8];
    zero_acc<8>(acc);
    gemm_step<8>(Xl, Wl, acc, wv, lr, lk);
    __syncthreads();
    write_h<8>(acc, Xl, b1, wv, lr, lk);
    stage_w<64>(W2t, Wl, tid);
    __syncthreads();

    floatx4 acc2[2][4];
    zero_acc<4>(acc2);
    gemm_step<4>(Xl, Wl, acc2, wv, lr, lk);
    epilogue<64, false, true, true>(acc2, b2, Yout, row0, n, wv, lr, lk);
}

// ---------------------------------------------------------------------------
// Single GEMM with BatchNorm+ReLU folded into X staging; coefs computed
// in-kernel from raw sums/sumsq.
// ---------------------------------------------------------------------------
__global__ __launch_bounds__(256, 2) void gemm_bnf_kernel(
    const ushort* __restrict__ Xg, const ushort* __restrict__ Wt,
    const float* __restrict__ sums, const float* __restrict__ sumsq,
    const float* __restrict__ g, const float* __restrict__ bb,
    ushort* __restrict__ Yout, int n) {
    __shared__ uint4 lds4[4096];
    __shared__ float scf[128], shf[128];
    uint4* Xl = lds4;
    uint4* Wl = lds4 + 2048;
    const int tid = threadIdx.x;
    const int row0 = blockIdx.x * 128;

    if (tid < 128) {
        const float inv_n = 1.0f / (float)NN;
        float m = sums[tid] * inv_n;
        float var = sumsq[tid] * inv_n - m * m;
        float sc = g[tid] * rsqrtf(var + BN_EPS);
        scf[tid] = sc;
        shf[tid] = bb[tid] - m * sc;
    }
    stage_w<128>(Wt, Wl, tid);
    __syncthreads();

    for (int c = tid; c < 2048; c += 256) {
        int r = c >> 4, kb = c & 15;
        int row = row0 + r;
        uint4 v = make_uint4(0, 0, 0, 0);
        if (row < n) v = ((const uint4*)(Xg + (size_t)row * 128))[kb];
        uint a[4] = {v.x, v.y, v.z, v.w};
        #pragma unroll
        for (int p = 0; p < 4; ++p) {
            int f0 = kb * 8 + p * 2;
            float lo = fmaxf(fmaf(bf2f_lo(a[p]), scf[f0], shf[f0]), 0.f);
            float hi = fmaxf(fmaf(bf2f_hi(a[p]), scf[f0 + 1], shf[f0 + 1]), 0.f);
            a[p] = pack_bf2(lo, hi);
        }
        Xl[r * 16 + (kb ^ (r & 15))] = make_uint4(a[0], a[1], a[2], a[3]);
    }
    __syncthreads();

    const int wv = tid >> 6, lane = tid & 63;
    const int lr = lane & 15, lk = lane >> 4;

    floatx4 acc[2][8];
    zero_acc<8>(acc);
    gemm_step<8>(Xl, Wl, acc, wv, lr, lk);
    epilogue<128, false, false, false>(acc, nullptr, Yout, row0, n, wv, lr, lk);
}

// ---------------------------------------------------------------------------
// Aggregation (bf16 rows): out[i] = sum_e h[src_e]*w_e + h[i]*dinv^2 + bias
// One wave per node; lane owns 2 features. f32 accum; packed int2 edges.
// Edge loop unrolled x8: halves the csr->gather serial round-trips per node
// (deg~16: 4 batches -> 2) and doubles outstanding gathers.
// ---------------------------------------------------------------------------
__global__ __launch_bounds__(256) void agg16_kernel(const ushort* __restrict__ h,
                                                    const float* __restrict__ dinv,
                                                    const int* __restrict__ off,
                                                    const int2* __restrict__ csr,
                                                    const float* __restrict__ bias,
                                                    ushort* __restrict__ out, int n) {
    int i = (blockIdx.x * 256 + threadIdx.x) >> 6;
    if (i >= n) return;
    int lane = threadIdx.x & 63;

    const uint* __restrict__ hq = (const uint*)h;
    float di = dinv[i];
    float sw = di * di;
    uint u = hq[(size_t)i * 64 + lane];
    float a0 = bf2f_lo(u) * sw, a1 = bf2f_hi(u) * sw;

    const int s0 = off[i], s1 = off[i + 1];
    int j = s0;
    for (; j + 8 <= s1; j += 8) {
        int2 e0 = csr[j + 0], e1 = csr[j + 1], e2 = csr[j + 2], e3 = csr[j + 3];
        int2 e4 = csr[j + 4], e5 = csr[j + 5], e6 = csr[j + 6], e7 = csr[j + 7];
        uint u0 = hq[(size_t)e0.x * 64 + lane];
        uint u1 = hq[(size_t)e1.x * 64 + lane];
        uint u2 = hq[(size_t)e2.x * 64 + lane];
        uint u3 = hq[(size_t)e3.x * 64 + lane];
        uint u4 = hq[(size_t)e4.x * 64 + lane];
        uint u5 = hq[(size_t)e5.x * 64 + lane];
        uint u6 = hq[(size_t)e6.x * 64 + lane];
        uint u7 = hq[(size_t)e7.x * 64 + lane];
        float w0 = __builtin_bit_cast(float, e0.y), w1 = __builtin_bit_cast(float, e1.y);
        float w2 = __builtin_bit_cast(float, e2.y), w3 = __builtin_bit_cast(float, e3.y);
        float w4 = __builtin_bit_cast(float, e4.y), w5 = __builtin_bit_cast(float, e5.y);
        float w6 = __builtin_bit_cast(float, e6.y), w7 = __builtin_bit_cast(float, e7.y);
        a0 += bf2f_lo(u0) * w0 + bf2f_lo(u1) * w1 + bf2f_lo(u2) * w2 + bf2f_lo(u3) * w3
            + bf2f_lo(u4) * w4 + bf2f_lo(u5) * w5 + bf2f_lo(u6) * w6 + bf2f_lo(u7) * w7;
        a1 += bf2f_hi(u0) * w0 + bf2f_hi(u1) * w1 + bf2f_hi(u2) * w2 + bf2f_hi(u3) * w3
            + bf2f_hi(u4) * w4 + bf2f_hi(u5) * w5 + bf2f_hi(u6) * w6 + bf2f_hi(u7) * w7;
    }
    for (; j + 4 <= s1; j += 4) {
        int2 e0 = csr[j + 0], e1 = csr[j + 1], e2 = csr[j + 2], e3 = csr[j + 3];
        uint u0 = hq[(size_t)e0.x * 64 + lane];
        uint u1 = hq[(size_t)e1.x * 64 + lane];
        uint u2 = hq[(size_t)e2.x * 64 + lane];
        uint u3 = hq[(size_t)e3.x * 64 + lane];
        float w0 = __builtin_bit_cast(float, e0.y), w1 = __builtin_bit_cast(float, e1.y);
        float w2 = __builtin_bit_cast(float, e2.y), w3 = __builtin_bit_cast(float, e3.y);
        a0 += bf2f_lo(u0) * w0 + bf2f_lo(u1) * w1 + bf2f_lo(u2) * w2 + bf2f_lo(u3) * w3;
        a1 += bf2f_hi(u0) * w0 + bf2f_hi(u1) * w1 + bf2f_hi(u2) * w2 + bf2f_hi(u3) * w3;
    }
    for (; j < s1; ++j) {
        int2 e = csr[j];
        float w = __builtin_bit_cast(float, e.y);
        uint uv = hq[(size_t)e.x * 64 + lane];
        a0 += bf2f_lo(uv) * w;
        a1 += bf2f_hi(uv) * w;
    }

    float2 b2 = ((const float2*)bias)[lane];
    a0 += b2.x; a1 += b2.y;
    ((uint*)out)[(size_t)i * 64 + lane] = pack_bf2(a0, a1);
}

// ---------------------------------------------------------------------------
// BatchNorm statistics: vectorized uint4 (8 bf16) loads, LDS reduce, atomics.
// ---------------------------------------------------------------------------
__global__ __launch_bounds__(256) void bn_stats16_kernel(const ushort* __restrict__ x,
                                                         float* __restrict__ sums,
                                                         float* __restrict__ sumsq, int n) {
    __shared__ float ls[128], lq[128];
    int tid = threadIdx.x;
    if (tid < 128) { ls[tid] = 0.f; lq[tid] = 0.f; }
    __syncthreads();
    int fg = tid & 15, rg = tid >> 4;
    float s[8] = {}, q[8] = {};
    for (int r = blockIdx.x * 16 + rg; r < n; r += gridDim.x * 16) {
        uint4 v = ((const uint4*)(x + (size_t)r * 128))[fg];
        uint a[4] = {v.x, v.y, v.z, v.w};
        #pragma unroll
        for (int p = 0; p < 4; ++p) {
            float lo = bf2f_lo(a[p]), hi = bf2f_hi(a[p]);
            s[2 * p] += lo;     q[2 * p] += lo * lo;
            s[2 * p + 1] += hi; q[2 * p + 1] += hi * hi;
        }
    }
    #pragma unroll
    for (int k = 0; k < 8; ++k) {
        atomicAdd(&ls[fg * 8 + k], s[k]);
        atomicAdd(&lq[fg * 8 + k], q[k]);
    }
    __syncthreads();
    if (tid < 128) {
        atomicAdd(&sums[tid], ls[tid]);
        atomicAdd(&sumsq[tid], lq[tid]);
    }
}

// ---------------------------------------------------------------------------
extern "C" void kernel_launch(void* const* d_in, const int* in_sizes, int n_in,
                              void* d_out, int out_size, void* d_ws, size_t ws_size,
                              hipStream_t stream) {
    const float* x        = (const float*)d_in[0];
    const int*   ei       = (const int*)d_in[1];
    const float* pre_w1   = (const float*)d_in[2];
    const float* pre_b1   = (const float*)d_in[3];
    const float* pre_w2   = (const float*)d_in[4];
    const float* pre_b2   = (const float*)d_in[5];
    const float* conv_w0  = (const float*)d_in[6];
    const float* conv_b0  = (const float*)d_in[7];
    const float* conv_w1  = (const float*)d_in[8];
    const float* conv_b1  = (const float*)d_in[9];
    const float* conv_w2  = (const float*)d_in[10];
    const float* conv_b2  = (const float*)d_in[11];
    const float* bn_g0    = (const float*)d_in[12];
    const float* bn_b0    = (const float*)d_in[13];
    const float* bn_g1    = (const float*)d_in[14];
    const float* bn_b1    = (const float*)d_in[15];
    const float* post_w1  = (const float*)d_in[16];
    const float* post_b1  = (const float*)d_in[17];
    const float* post_w2  = (const float*)d_in[18];
    const float* post_b2  = (const float*)d_in[19];
    float* out = (float*)d_out;

    const int n = NN, E = EE;
    const int NB = (n + 255) / 256;

    // Workspace layout (cnt followed by BN sums region -> single memset)
    char* w = (char*)d_ws;
    int* cnt    = (int*)w;   w += (size_t)n * 4;          // 16B-aligned
    float* bns0 = (float*)w; // sums0, sumsq0, sums1, sumsq1 (512 floats)
    float* bnq0 = bns0 + 128;
    float* bns1 = bns0 + 256;
    float* bnq1 = bns0 + 384;
    w += align_up(512 * 4, 512);
    int* cursor = (int*)w;   w += align_up((size_t)n * 4, 512);
    int* bsum   = (int*)w;   w += align_up(256 * 4, 512);
    int* off    = (int*)w;   w += align_up((size_t)(n + 1) * 4, 512);
    float* dinv = (float*)w; w += align_up((size_t)n * 4, 512);
    int2* csr   = (int2*)w;  w += align_up((size_t)E * 8, 512);
    ushort* wt_pre1  = (ushort*)w; w += align_up(128 * 128 * 2, 512);
    ushort* wt_pre2  = (ushort*)w; w += align_up(128 * 128 * 2, 512);
    ushort* wt_c0    = (ushort*)w; w += align_up(128 * 128 * 2, 512);
    ushort* wt_c1    = (ushort*)w; w += align_up(128 * 128 * 2, 512);
    ushort* wt_c2    = (ushort*)w; w += align_up(128 * 128 * 2, 512);
    ushort* wt_post1 = (ushort*)w; w += align_up(128 * 128 * 2, 512);
    ushort* wt_post2 = (ushort*)w; w += align_up(64 * 128 * 2, 512);
    ushort* P = (ushort*)w; w += align_up((size_t)n * 128 * 2, 512);
    ushort* Q = (ushort*)w; w += align_up((size_t)n * 128 * 2, 512);
    ushort* R = (ushort*)w; w += align_up((size_t)n * 128 * 2, 512);

    hipMemsetAsync(cnt, 0, (size_t)n * 4 + 512 * 4, stream);

    // Weight transposes/casts (one dispatch)
    tcast_all_kernel<<<dim3(64, 7), 256, 0, stream>>>(
        pre_w1, pre_w2, conv_w0, conv_w1, conv_w2, post_w1, post_w2,
        wt_pre1, wt_pre2, wt_c0, wt_c1, wt_c2, wt_post1, wt_post2);

    // Graph preprocessing
    cnt_kernel<<<(E / 4 + 255) / 256, 256, 0, stream>>>(ei, cnt, E);
    scan_part_kernel<<<NB, 256, 0, stream>>>(cnt, off, bsum, dinv, n);
    scan_bsum_kernel<<<1, 256, 0, stream>>>(bsum, NB);
    scan_add_kernel<<<NB, 256, 0, stream>>>(off, bsum, cursor, n);
    fill_kernel<<<(E + 255) / 256, 256, 0, stream>>>(ei, cursor, csr, dinv, E);

    const int gb = (n + 127) / 128;
    const int agg_blocks = (n * 64 + 255) / 256;   // one wave per node

    // pre-MLP + conv0 (fused)
    fused_pre_kernel<<<gb, 256, 0, stream>>>(x, wt_pre1, pre_b1, wt_pre2, pre_b2, wt_c0, P, n);
    agg16_kernel<<<agg_blocks, 256, 0, stream>>>(P, dinv, off, csr, conv_b0, Q, n);
    bn_stats16_kernel<<<256, 256, 0, stream>>>(Q, bns0, bnq0, n);

    // conv1 (BN0 fold, coef in-kernel)
    gemm_bnf_kernel<<<gb, 256, 0, stream>>>(Q, wt_c1, bns0, bnq0, bn_g0, bn_b0, P, n);
    agg16_kernel<<<agg_blocks, 256, 0, stream>>>(P, dinv, off, csr, conv_b1, R, n);
    bn_stats16_kernel<<<256, 256, 0, stream>>>(R, bns1, bnq1, n);

    // conv2 (BN1 fold)
    gemm_bnf_kernel<<<gb, 256, 0, stream>>>(R, wt_c2, bns1, bnq1, bn_g1, bn_b1, P, n);
    agg16_kernel<<<agg_blocks, 256, 0, stream>>>(P, dinv, off, csr, conv_b2, Q, n);

    // post-MLP (fused)
    fused_post_kernel<<<gb, 256, 0, stream>>>(Q, wt_post1, post_b1, wt_post2, post_b2, out, n);
}

// Round 9
// 380.254 us; speedup vs baseline: 1.1969x; 1.0702x over previous
//
#include <hip/hip_runtime.h>
#include <hip/hip_bf16.h>

// Problem constants (fixed by the reference setup)
#define NN 50000
#define EE 800000
#define DIN 128
#define HH 128
#define DOUT 64
#define BN_EPS 1e-5f

typedef __attribute__((ext_vector_type(8))) short short8;   // 8 bf16 (4 VGPRs)
typedef __attribute__((ext_vector_type(4))) float floatx4;  // MFMA acc

static inline size_t align_up(size_t x, size_t a) { return (x + a - 1) & ~(a - 1); }

// bf16 <-> f32 helpers (RNE round)
__device__ __forceinline__ float bf2f(ushort u) {
    uint v = ((uint)u) << 16;
    return __builtin_bit_cast(float, v);
}
__device__ __forceinline__ float bf2f_lo(uint u) { return __builtin_bit_cast(float, u << 16); }
__device__ __forceinline__ float bf2f_hi(uint u) { return __builtin_bit_cast(float, u & 0xffff0000u); }
__device__ __forceinline__ ushort f2bf(float f) {
    uint u = __builtin_bit_cast(uint, f);
    u += 0x7fff + ((u >> 16) & 1);
    return (ushort)(u >> 16);
}
__device__ __forceinline__ uint pack_bf2(float lo, float hi) {
    return (uint)f2bf(lo) | ((uint)f2bf(hi) << 16);
}

// ---------------------------------------------------------------------------
// All 7 weights in one dispatch: W[k][f] f32 -> Wt[f][k] bf16 (k contiguous)
// ---------------------------------------------------------------------------
__global__ void tcast_all_kernel(const float* __restrict__ s0, const float* __restrict__ s1,
                                 const float* __restrict__ s2, const float* __restrict__ s3,
                                 const float* __restrict__ s4, const float* __restrict__ s5,
                                 const float* __restrict__ s6,
                                 ushort* __restrict__ d0, ushort* __restrict__ d1,
                                 ushort* __restrict__ d2, ushort* __restrict__ d3,
                                 ushort* __restrict__ d4, ushort* __restrict__ d5,
                                 ushort* __restrict__ d6) {
    const float* src; ushort* dst; int F = 128;
    switch (blockIdx.y) {
        case 0: src = s0; dst = d0; break;
        case 1: src = s1; dst = d1; break;
        case 2: src = s2; dst = d2; break;
        case 3: src = s3; dst = d3; break;
        case 4: src = s4; dst = d4; break;
        case 5: src = s5; dst = d5; break;
        default: src = s6; dst = d6; F = 64; break;
    }
    int t = blockIdx.x * 256 + threadIdx.x;
    if (t >= F * 128) return;
    int f = t >> 7, k = t & 127;
    dst[t] = f2bf(src[(size_t)k * F + f]);
}

// ---------------------------------------------------------------------------
// Graph preprocessing
// ---------------------------------------------------------------------------
// Count in-edges AND record each edge's rank among same-dst edges.
// The rank makes the later fill pass atomic-free.
__global__ void cnt_kernel(const int* __restrict__ ei, int* __restrict__ cnt,
                           int* __restrict__ rank, int E) {
    int e = (blockIdx.x * 256 + threadIdx.x) * 4;
    if (e + 3 < E) {
        int4 d = *(const int4*)(ei + E + e);
        int4 r;
        r.x = atomicAdd(&cnt[d.x], 1);
        r.y = atomicAdd(&cnt[d.y], 1);
        r.z = atomicAdd(&cnt[d.z], 1);
        r.w = atomicAdd(&cnt[d.w], 1);
        *(int4*)(rank + e) = r;
    } else {
        for (; e < E; ++e) rank[e] = atomicAdd(&cnt[ei[E + e]], 1);
    }
}

__device__ __forceinline__ void block_scan256(int v, int* lsum, int& excl, int& total) {
    int lane = threadIdx.x & 63, w = threadIdx.x >> 6;
    int inc = v;
    #pragma unroll
    for (int s = 1; s < 64; s <<= 1) {
        int t = __shfl_up(inc, s);
        if (lane >= s) inc += t;
    }
    if (lane == 63) lsum[w] = inc;
    __syncthreads();
    int pre = 0;
    #pragma unroll
    for (int k = 0; k < 4; ++k)
        if (k < w) pre += lsum[k];
    excl = pre + inc - v;
    total = lsum[0] + lsum[1] + lsum[2] + lsum[3];
    __syncthreads();
}

// partial exclusive scan into off; block sums; dinv fused in
__global__ void scan_part_kernel(const int* __restrict__ cnt, int* __restrict__ off,
                                 int* __restrict__ bsum, float* __restrict__ dinv, int n) {
    __shared__ int lsum[4];
    int i = blockIdx.x * 256 + threadIdx.x;
    int v = (i < n) ? cnt[i] : 0;
    int excl, total;
    block_scan256(v, lsum, excl, total);
    if (i < n) {
        off[i] = excl;
        dinv[i] = rsqrtf((float)(v + 1));
    }
    if (threadIdx.x == 0) bsum[blockIdx.x] = total;
}

__global__ void scan_bsum_kernel(int* __restrict__ bsum, int nb) {
    __shared__ int lsum[4];
    int t = threadIdx.x;
    int v = (t < nb) ? bsum[t] : 0;
    int excl, total;
    block_scan256(v, lsum, excl, total);
    if (t < nb) bsum[t] = excl;
}

// finalize off
__global__ void scan_add_kernel(int* __restrict__ off, const int* __restrict__ bsum, int n) {
    int i = blockIdx.x * 256 + threadIdx.x;
    if (i < n) off[i] += bsum[blockIdx.x];
    if (i == 0) off[n] = EE;
}

// Atomic-free scatter: pos = off[d] + rank[e]. All loads independent
// (off/dinv tables are L2-hot, 200KB/200KB); 2 edges/thread.
__global__ void fill_kernel(const int* __restrict__ ei, const int* __restrict__ off,
                            const int* __restrict__ rank, int2* __restrict__ csr,
                            const float* __restrict__ dinv, int E) {
    int e = (blockIdx.x * 256 + threadIdx.x) * 2;
    if (e + 1 < E) {
        int2 s2 = *(const int2*)(ei + e);
        int2 d2 = *(const int2*)(ei + E + e);
        int2 r2 = *(const int2*)(rank + e);
        float wa = dinv[s2.x] * dinv[d2.x];
        float wb = dinv[s2.y] * dinv[d2.y];
        int pa = off[d2.x] + r2.x;
        int pb = off[d2.y] + r2.y;
        csr[pa] = make_int2(s2.x, __builtin_bit_cast(int, wa));
        csr[pb] = make_int2(s2.y, __builtin_bit_cast(int, wb));
    } else if (e < E) {
        int s = ei[e];
        int d = ei[E + e];
        float w = dinv[s] * dinv[d];
        csr[off[d] + rank[e]] = make_int2(s, __builtin_bit_cast(int, w));
    }
}

// ---------------------------------------------------------------------------
// Shared MFMA building blocks. LDS layout: [row/f][16 uint4-chunks] with
// chunk index XOR-swizzled by (row&15) -> ds_read_b128 is 2-way (free).
// ---------------------------------------------------------------------------
template <int NCG>
__device__ __forceinline__ void zero_acc(floatx4 (&acc)[2][NCG]) {
    #pragma unroll
    for (int rg = 0; rg < 2; ++rg)
        #pragma unroll
        for (int cg = 0; cg < NCG; ++cg)
            acc[rg][cg] = (floatx4){0.f, 0.f, 0.f, 0.f};
}

template <int FO>
__device__ __forceinline__ void stage_w(const ushort* __restrict__ Wt, uint4* Wl, int tid) {
    #pragma unroll
    for (int c = tid; c < FO * 16; c += 256) {
        int f = c >> 4, kb = c & 15;
        Wl[f * 16 + (kb ^ (f & 15))] = ((const uint4*)Wt)[c];
    }
}

template <int NCG>
__device__ __forceinline__ void gemm_step(const uint4* Xl, const uint4* Wl,
                                          floatx4 (&acc)[2][NCG], int wv, int lr, int lk) {
    #pragma unroll
    for (int ks = 0; ks < 4; ++ks) {
        int kb = ks * 4 + lk;
        int swz = kb ^ lr;
        short8 a0 = *(const short8*)&Xl[(wv * 32 + lr) * 16 + swz];
        short8 a1 = *(const short8*)&Xl[(wv * 32 + 16 + lr) * 16 + swz];
        #pragma unroll
        for (int cg = 0; cg < NCG; ++cg) {
            short8 b = *(const short8*)&Wl[(cg * 16 + lr) * 16 + swz];
            acc[0][cg] = __builtin_amdgcn_mfma_f32_16x16x32_bf16(a0, b, acc[0][cg], 0, 0, 0);
            acc[1][cg] = __builtin_amdgcn_mfma_f32_16x16x32_bf16(a1, b, acc[1][cg], 0, 0, 0);
        }
    }
}

// write H = relu(acc + bias) back into the X LDS buffer (bf16, same swizzle)
template <int NCG>
__device__ __forceinline__ void write_h(floatx4 (&acc)[2][NCG], uint4* Xl,
                                        const float* __restrict__ bias,
                                        int wv, int lr, int lk) {
    ushort* Xs = (ushort*)Xl;
    #pragma unroll
    for (int rg = 0; rg < 2; ++rg)
        #pragma unroll
        for (int cg = 0; cg < NCG; ++cg) {
            int col = cg * 16 + lr;
            float bv = bias[col];
            #pragma unroll
            for (int j = 0; j < 4; ++j) {
                int row = wv * 32 + rg * 16 + lk * 4 + j;
                float o = fmaxf(acc[rg][cg][j] + bv, 0.f);
                Xs[(row * 16 + ((col >> 3) ^ (row & 15))) * 8 + (col & 7)] = f2bf(o);
            }
        }
}

template <int FOUT, bool RELU, bool BIAS, bool OUTF32>
__device__ __forceinline__ void epilogue(floatx4 (&acc)[2][FOUT / 16],
                                         const float* __restrict__ bias, void* Yout,
                                         int row0, int n, int wv, int lr, int lk) {
    #pragma unroll
    for (int rg = 0; rg < 2; ++rg) {
        int rbase = row0 + wv * 32 + rg * 16 + lk * 4;
        #pragma unroll
        for (int cg = 0; cg < FOUT / 16; ++cg) {
            int col = cg * 16 + lr;
            float bv = BIAS ? bias[col] : 0.f;
            #pragma unroll
            for (int j = 0; j < 4; ++j) {
                int r = rbase + j;
                if (r < n) {
                    float o = acc[rg][cg][j] + bv;
                    if (RELU) o = fmaxf(o, 0.f);
                    if (OUTF32)
                        ((float*)Yout)[(size_t)r * FOUT + col] = o;
                    else
                        ((ushort*)Yout)[(size_t)r * FOUT + col] = f2bf(o);
                }
            }
        }
    }
}

// ---------------------------------------------------------------------------
// Fused pre-MLP + conv0 GEMM: P = relu(relu(X@W1+b1)@W2+b2)@W0c
// ---------------------------------------------------------------------------
__global__ __launch_bounds__(256, 2) void fused_pre_kernel(
    const float* __restrict__ Xg, const ushort* __restrict__ W1t, const float* __restrict__ b1,
    const ushort* __restrict__ W2t, const float* __restrict__ b2,
    const ushort* __restrict__ W3t, ushort* __restrict__ Yout, int n) {
    __shared__ uint4 lds4[4096];
    uint4* Xl = lds4;
    uint4* Wl = lds4 + 2048;
    const int tid = threadIdx.x;
    const int row0 = blockIdx.x * 128;

    // stage X with f32->bf16 cast
    for (int c = tid; c < 2048; c += 256) {
        int r = c >> 4, kb = c & 15;
        int row = row0 + r;
        uint4 v = make_uint4(0, 0, 0, 0);
        if (row < n) {
            const float4* p = (const float4*)(Xg + (size_t)row * 128 + kb * 8);
            float4 x0 = p[0], x1 = p[1];
            v.x = pack_bf2(x0.x, x0.y);
            v.y = pack_bf2(x0.z, x0.w);
            v.z = pack_bf2(x1.x, x1.y);
            v.w = pack_bf2(x1.z, x1.w);
        }
        Xl[r * 16 + (kb ^ (r & 15))] = v;
    }
    stage_w<128>(W1t, Wl, tid);
    __syncthreads();

    const int wv = tid >> 6, lane = tid & 63;
    const int lr = lane & 15, lk = lane >> 4;

    floatx4 acc[2][8];
    zero_acc<8>(acc);
    gemm_step<8>(Xl, Wl, acc, wv, lr, lk);
    __syncthreads();
    write_h<8>(acc, Xl, b1, wv, lr, lk);
    stage_w<128>(W2t, Wl, tid);
    __syncthreads();

    zero_acc<8>(acc);
    gemm_step<8>(Xl, Wl, acc, wv, lr, lk);
    __syncthreads();
    write_h<8>(acc, Xl, b2, wv, lr, lk);
    stage_w<128>(W3t, Wl, tid);
    __syncthreads();

    zero_acc<8>(acc);
    gemm_step<8>(Xl, Wl, acc, wv, lr, lk);
    epilogue<128, false, false, false>(acc, nullptr, Yout, row0, n, wv, lr, lk);
}

// ---------------------------------------------------------------------------
// Fused post-MLP: out = relu(X@W1+b1)@W2 + b2   (f32 output, DOUT=64)
// ---------------------------------------------------------------------------
__global__ __launch_bounds__(256, 2) void fused_post_kernel(
    const ushort* __restrict__ Xg, const ushort* __restrict__ W1t, const float* __restrict__ b1,
    const ushort* __restrict__ W2t, const float* __restrict__ b2,
    float* __restrict__ Yout, int n) {
    __shared__ uint4 lds4[4096];
    uint4* Xl = lds4;
    uint4* Wl = lds4 + 2048;
    const int tid = threadIdx.x;
    const int row0 = blockIdx.x * 128;

    for (int c = tid; c < 2048; c += 256) {
        int r = c >> 4, kb = c & 15;
        int row = row0 + r;
        uint4 v = make_uint4(0, 0, 0, 0);
        if (row < n) v = ((const uint4*)(Xg + (size_t)row * 128))[kb];
        Xl[r * 16 + (kb ^ (r & 15))] = v;
    }
    stage_w<128>(W1t, Wl, tid);
    __syncthreads();

    const int wv = tid >> 6, lane = tid & 63;
    const int lr = lane & 15, lk = lane >> 4;

    floatx4 acc[2][8];
    zero_acc<8>(acc);
    gemm_step<8>(Xl, Wl, acc, wv, lr, lk);
    __syncthreads();
    write_h<8>(acc, Xl, b1, wv, lr, lk);
    stage_w<64>(W2t, Wl, tid);
    __syncthreads();

    floatx4 acc2[2][4];
    zero_acc<4>(acc2);
    gemm_step<4>(Xl, Wl, acc2, wv, lr, lk);
    epilogue<64, false, true, true>(acc2, b2, Yout, row0, n, wv, lr, lk);
}

// ---------------------------------------------------------------------------
// Single GEMM with BatchNorm+ReLU folded into X staging; coefs computed
// in-kernel from raw sums/sumsq.
// ---------------------------------------------------------------------------
__global__ __launch_bounds__(256, 2) void gemm_bnf_kernel(
    const ushort* __restrict__ Xg, const ushort* __restrict__ Wt,
    const float* __restrict__ sums, const float* __restrict__ sumsq,
    const float* __restrict__ g, const float* __restrict__ bb,
    ushort* __restrict__ Yout, int n) {
    __shared__ uint4 lds4[4096];
    __shared__ float scf[128], shf[128];
    uint4* Xl = lds4;
    uint4* Wl = lds4 + 2048;
    const int tid = threadIdx.x;
    const int row0 = blockIdx.x * 128;

    if (tid < 128) {
        const float inv_n = 1.0f / (float)NN;
        float m = sums[tid] * inv_n;
        float var = sumsq[tid] * inv_n - m * m;
        float sc = g[tid] * rsqrtf(var + BN_EPS);
        scf[tid] = sc;
        shf[tid] = bb[tid] - m * sc;
    }
    stage_w<128>(Wt, Wl, tid);
    __syncthreads();

    for (int c = tid; c < 2048; c += 256) {
        int r = c >> 4, kb = c & 15;
        int row = row0 + r;
        uint4 v = make_uint4(0, 0, 0, 0);
        if (row < n) v = ((const uint4*)(Xg + (size_t)row * 128))[kb];
        uint a[4] = {v.x, v.y, v.z, v.w};
        #pragma unroll
        for (int p = 0; p < 4; ++p) {
            int f0 = kb * 8 + p * 2;
            float lo = fmaxf(fmaf(bf2f_lo(a[p]), scf[f0], shf[f0]), 0.f);
            float hi = fmaxf(fmaf(bf2f_hi(a[p]), scf[f0 + 1], shf[f0 + 1]), 0.f);
            a[p] = pack_bf2(lo, hi);
        }
        Xl[r * 16 + (kb ^ (r & 15))] = make_uint4(a[0], a[1], a[2], a[3]);
    }
    __syncthreads();

    const int wv = tid >> 6, lane = tid & 63;
    const int lr = lane & 15, lk = lane >> 4;

    floatx4 acc[2][8];
    zero_acc<8>(acc);
    gemm_step<8>(Xl, Wl, acc, wv, lr, lk);
    epilogue<128, false, false, false>(acc, nullptr, Yout, row0, n, wv, lr, lk);
}

// ---------------------------------------------------------------------------
// Aggregation (bf16 rows): out[i] = sum_e h[src_e]*w_e + h[i]*dinv^2 + bias
// One wave per node; lane owns 2 features. f32 accum; packed int2 edges.
// Edge loop unrolled x8. Non-temporal out store: the 25.6 MB streaming write
// must not evict the gather-hot h table from L2.
// ---------------------------------------------------------------------------
__global__ __launch_bounds__(256) void agg16_kernel(const ushort* __restrict__ h,
                                                    const float* __restrict__ dinv,
                                                    const int* __restrict__ off,
                                                    const int2* __restrict__ csr,
                                                    const float* __restrict__ bias,
                                                    ushort* __restrict__ out, int n) {
    int i = (blockIdx.x * 256 + threadIdx.x) >> 6;
    if (i >= n) return;
    int lane = threadIdx.x & 63;

    const uint* __restrict__ hq = (const uint*)h;
    float di = dinv[i];
    float sw = di * di;
    uint u = hq[(size_t)i * 64 + lane];
    float a0 = bf2f_lo(u) * sw, a1 = bf2f_hi(u) * sw;

    const int s0 = off[i], s1 = off[i + 1];
    int j = s0;
    for (; j + 8 <= s1; j += 8) {
        int2 e0 = csr[j + 0], e1 = csr[j + 1], e2 = csr[j + 2], e3 = csr[j + 3];
        int2 e4 = csr[j + 4], e5 = csr[j + 5], e6 = csr[j + 6], e7 = csr[j + 7];
        uint u0 = hq[(size_t)e0.x * 64 + lane];
        uint u1 = hq[(size_t)e1.x * 64 + lane];
        uint u2 = hq[(size_t)e2.x * 64 + lane];
        uint u3 = hq[(size_t)e3.x * 64 + lane];
        uint u4 = hq[(size_t)e4.x * 64 + lane];
        uint u5 = hq[(size_t)e5.x * 64 + lane];
        uint u6 = hq[(size_t)e6.x * 64 + lane];
        uint u7 = hq[(size_t)e7.x * 64 + lane];
        float w0 = __builtin_bit_cast(float, e0.y), w1 = __builtin_bit_cast(float, e1.y);
        float w2 = __builtin_bit_cast(float, e2.y), w3 = __builtin_bit_cast(float, e3.y);
        float w4 = __builtin_bit_cast(float, e4.y), w5 = __builtin_bit_cast(float, e5.y);
        float w6 = __builtin_bit_cast(float, e6.y), w7 = __builtin_bit_cast(float, e7.y);
        a0 += bf2f_lo(u0) * w0 + bf2f_lo(u1) * w1 + bf2f_lo(u2) * w2 + bf2f_lo(u3) * w3
            + bf2f_lo(u4) * w4 + bf2f_lo(u5) * w5 + bf2f_lo(u6) * w6 + bf2f_lo(u7) * w7;
        a1 += bf2f_hi(u0) * w0 + bf2f_hi(u1) * w1 + bf2f_hi(u2) * w2 + bf2f_hi(u3) * w3
            + bf2f_hi(u4) * w4 + bf2f_hi(u5) * w5 + bf2f_hi(u6) * w6 + bf2f_hi(u7) * w7;
    }
    for (; j + 4 <= s1; j += 4) {
        int2 e0 = csr[j + 0], e1 = csr[j + 1], e2 = csr[j + 2], e3 = csr[j + 3];
        uint u0 = hq[(size_t)e0.x * 64 + lane];
        uint u1 = hq[(size_t)e1.x * 64 + lane];
        uint u2 = hq[(size_t)e2.x * 64 + lane];
        uint u3 = hq[(size_t)e3.x * 64 + lane];
        float w0 = __builtin_bit_cast(float, e0.y), w1 = __builtin_bit_cast(float, e1.y);
        float w2 = __builtin_bit_cast(float, e2.y), w3 = __builtin_bit_cast(float, e3.y);
        a0 += bf2f_lo(u0) * w0 + bf2f_lo(u1) * w1 + bf2f_lo(u2) * w2 + bf2f_lo(u3) * w3;
        a1 += bf2f_hi(u0) * w0 + bf2f_hi(u1) * w1 + bf2f_hi(u2) * w2 + bf2f_hi(u3) * w3;
    }
    for (; j < s1; ++j) {
        int2 e = csr[j];
        float w = __builtin_bit_cast(float, e.y);
        uint uv = hq[(size_t)e.x * 64 + lane];
        a0 += bf2f_lo(uv) * w;
        a1 += bf2f_hi(uv) * w;
    }

    float2 b2 = ((const float2*)bias)[lane];
    a0 += b2.x; a1 += b2.y;
    __builtin_nontemporal_store(pack_bf2(a0, a1), (uint*)out + (size_t)i * 64 + lane);
}

// ---------------------------------------------------------------------------
// BatchNorm statistics: vectorized uint4 (8 bf16) loads, LDS reduce, atomics.
// ---------------------------------------------------------------------------
__global__ __launch_bounds__(256) void bn_stats16_kernel(const ushort* __restrict__ x,
                                                         float* __restrict__ sums,
                                                         float* __restrict__ sumsq, int n) {
    __shared__ float ls[128], lq[128];
    int tid = threadIdx.x;
    if (tid < 128) { ls[tid] = 0.f; lq[tid] = 0.f; }
    __syncthreads();
    int fg = tid & 15, rg = tid >> 4;
    float s[8] = {}, q[8] = {};
    for (int r = blockIdx.x * 16 + rg; r < n; r += gridDim.x * 16) {
        uint4 v = ((const uint4*)(x + (size_t)r * 128))[fg];
        uint a[4] = {v.x, v.y, v.z, v.w};
        #pragma unroll
        for (int p = 0; p < 4; ++p) {
            float lo = bf2f_lo(a[p]), hi = bf2f_hi(a[p]);
            s[2 * p] += lo;     q[2 * p] += lo * lo;
            s[2 * p + 1] += hi; q[2 * p + 1] += hi * hi;
        }
    }
    #pragma unroll
    for (int k = 0; k < 8; ++k) {
        atomicAdd(&ls[fg * 8 + k], s[k]);
        atomicAdd(&lq[fg * 8 + k], q[k]);
    }
    __syncthreads();
    if (tid < 128) {
        atomicAdd(&sums[tid], ls[tid]);
        atomicAdd(&sumsq[tid], lq[tid]);
    }
}

// ---------------------------------------------------------------------------
extern "C" void kernel_launch(void* const* d_in, const int* in_sizes, int n_in,
                              void* d_out, int out_size, void* d_ws, size_t ws_size,
                              hipStream_t stream) {
    const float* x        = (const float*)d_in[0];
    const int*   ei       = (const int*)d_in[1];
    const float* pre_w1   = (const float*)d_in[2];
    const float* pre_b1   = (const float*)d_in[3];
    const float* pre_w2   = (const float*)d_in[4];
    const float* pre_b2   = (const float*)d_in[5];
    const float* conv_w0  = (const float*)d_in[6];
    const float* conv_b0  = (const float*)d_in[7];
    const float* conv_w1  = (const float*)d_in[8];
    const float* conv_b1  = (const float*)d_in[9];
    const float* conv_w2  = (const float*)d_in[10];
    const float* conv_b2  = (const float*)d_in[11];
    const float* bn_g0    = (const float*)d_in[12];
    const float* bn_b0    = (const float*)d_in[13];
    const float* bn_g1    = (const float*)d_in[14];
    const float* bn_b1    = (const float*)d_in[15];
    const float* post_w1  = (const float*)d_in[16];
    const float* post_b1  = (const float*)d_in[17];
    const float* post_w2  = (const float*)d_in[18];
    const float* post_b2  = (const float*)d_in[19];
    float* out = (float*)d_out;

    const int n = NN, E = EE;
    const int NB = (n + 255) / 256;

    // Workspace layout (cnt followed by BN sums region -> single memset)
    char* w = (char*)d_ws;
    int* cnt    = (int*)w;   w += (size_t)n * 4;          // 16B-aligned
    float* bns0 = (float*)w; // sums0, sumsq0, sums1, sumsq1 (512 floats)
    float* bnq0 = bns0 + 128;
    float* bns1 = bns0 + 256;
    float* bnq1 = bns0 + 384;
    w += align_up(512 * 4, 512);
    int* rank   = (int*)w;   w += align_up((size_t)E * 4, 512);
    int* bsum   = (int*)w;   w += align_up(256 * 4, 512);
    int* off    = (int*)w;   w += align_up((size_t)(n + 1) * 4, 512);
    float* dinv = (float*)w; w += align_up((size_t)n * 4, 512);
    int2* csr   = (int2*)w;  w += align_up((size_t)E * 8, 512);
    ushort* wt_pre1  = (ushort*)w; w += align_up(128 * 128 * 2, 512);
    ushort* wt_pre2  = (ushort*)w; w += align_up(128 * 128 * 2, 512);
    ushort* wt_c0    = (ushort*)w; w += align_up(128 * 128 * 2, 512);
    ushort* wt_c1    = (ushort*)w; w += align_up(128 * 128 * 2, 512);
    ushort* wt_c2    = (ushort*)w; w += align_up(128 * 128 * 2, 512);
    ushort* wt_post1 = (ushort*)w; w += align_up(128 * 128 * 2, 512);
    ushort* wt_post2 = (ushort*)w; w += align_up(64 * 128 * 2, 512);
    ushort* P = (ushort*)w; w += align_up((size_t)n * 128 * 2, 512);
    ushort* Q = (ushort*)w; w += align_up((size_t)n * 128 * 2, 512);
    ushort* R = (ushort*)w; w += align_up((size_t)n * 128 * 2, 512);

    hipMemsetAsync(cnt, 0, (size_t)n * 4 + 512 * 4, stream);

    // Weight transposes/casts (one dispatch)
    tcast_all_kernel<<<dim3(64, 7), 256, 0, stream>>>(
        pre_w1, pre_w2, conv_w0, conv_w1, conv_w2, post_w1, post_w2,
        wt_pre1, wt_pre2, wt_c0, wt_c1, wt_c2, wt_post1, wt_post2);

    // Graph preprocessing (fill is atomic-free: rank precomputed in cnt)
    cnt_kernel<<<(E / 4 + 255) / 256, 256, 0, stream>>>(ei, cnt, rank, E);
    scan_part_kernel<<<NB, 256, 0, stream>>>(cnt, off, bsum, dinv, n);
    scan_bsum_kernel<<<1, 256, 0, stream>>>(bsum, NB);
    scan_add_kernel<<<NB, 256, 0, stream>>>(off, bsum, n);
    fill_kernel<<<(E / 2 + 255) / 256, 256, 0, stream>>>(ei, off, rank, csr, dinv, E);

    const int gb = (n + 127) / 128;
    const int agg_blocks = (n * 64 + 255) / 256;   // one wave per node

    // pre-MLP + conv0 (fused)
    fused_pre_kernel<<<gb, 256, 0, stream>>>(x, wt_pre1, pre_b1, wt_pre2, pre_b2, wt_c0, P, n);
    agg16_kernel<<<agg_blocks, 256, 0, stream>>>(P, dinv, off, csr, conv_b0, Q, n);
    bn_stats16_kernel<<<256, 256, 0, stream>>>(Q, bns0, bnq0, n);

    // conv1 (BN0 fold, coef in-kernel)
    gemm_bnf_kernel<<<gb, 256, 0, stream>>>(Q, wt_c1, bns0, bnq0, bn_g0, bn_b0, P, n);
    agg16_kernel<<<agg_blocks, 256, 0, stream>>>(P, dinv, off, csr, conv_b1, R, n);
    bn_stats16_kernel<<<256, 256, 0, stream>>>(R, bns1, bnq1, n);

    // conv2 (BN1 fold)
    gemm_bnf_kernel<<<gb, 256, 0, stream>>>(R, wt_c2, bns1, bnq1, bn_g1, bn_b1, P, n);
    agg16_kernel<<<agg_blocks, 256, 0, stream>>>(P, dinv, off, csr, conv_b2, Q, n);

    // post-MLP (fused)
    fused_post_kernel<<<gb, 256, 0, stream>>>(Q, wt_post1, post_b1, wt_post2, post_b2, out, n);
}